// Round 7
// baseline (1743.495 us; speedup 1.0000x reference)
//
#include <hip/hip_runtime.h>
#include <math.h>

#define NB 8
#define CDCT 64
#define HB 128
#define WB 128
#define EE 128
#define NHD 4
#define KS 7
#define PP 49
#define DFF 512
#define NLAY 4
#define HW (HB*WB)          // 16384
#define NPOS (NB*HB*WB)     // 131072
#define EPSV 1e-5f

typedef unsigned short u16;
typedef float f32x4 __attribute__((ext_vector_type(4)));
typedef short s16x8 __attribute__((ext_vector_type(8)));

__device__ __forceinline__ float bf2f(u16 u) {
    union { unsigned int i; float f; } c; c.i = ((unsigned int)u) << 16; return c.f;
}
__device__ __forceinline__ u16 f2bf(float f) {
    union { float f; unsigned int i; } c; c.f = f;
    unsigned int x = c.i;
    return (u16)((x + 0x7fffu + ((x >> 16) & 1u)) >> 16);
}
// GELU: sigmoid form of the tanh approximation (<=0.003 abs dev from erf-GELU,
// below bf16 rounding of h). 1 exp + 1 div instead of erff's ~25-30 VALU ops.
__device__ __forceinline__ float gelu_f(float x) {
    float t2 = 1.5957691216057308f * (x + 0.044715f * x * x * x);
    return x / (1.0f + __expf(-t2));
}

// ============ prep: transpose+convert transformer weights to bf16 ============
__global__ __launch_bounds__(256) void k_prep_qkvff(
    const float* __restrict__ qw, const float* __restrict__ kw, const float* __restrict__ vw,
    const float* __restrict__ fw1, const float* __restrict__ fw2,
    u16* __restrict__ wqkvt, u16* __restrict__ w1t, u16* __restrict__ w2t)
{
    int idx = blockIdx.x * 256 + threadIdx.x;      // < 720896
    int l = idx / 180224;
    int rem = idx - l * 180224;
    if (rem < 49152) {
        int n = rem >> 7, k2 = rem & 127;
        int mat = n >> 7, c = n & 127;
        const float* src = (mat == 0) ? qw : (mat == 1) ? kw : vw;
        wqkvt[l * 49152 + rem] = f2bf(src[l * 16384 + k2 * 128 + c]);
    } else if (rem < 114688) {
        int r2 = rem - 49152;
        int j = r2 >> 7, i = r2 & 127;
        w1t[l * 65536 + r2] = f2bf(fw1[l * 65536 + i * 512 + j]);
    } else {
        int r3 = rem - 114688;
        int e = r3 >> 9, d = r3 & 511;
        w2t[l * 65536 + r3] = f2bf(fw2[l * 65536 + d * 128 + e]);
    }
}

// prep conv/enc-proj/decoder weights: wtap[tap(9)][co(64)][ci(64)], w2b[e][ci], dwb[co][e]
__global__ __launch_bounds__(256) void k_prep_conv(
    const float* __restrict__ ec1w, const float* __restrict__ ec2w,
    const float* __restrict__ dw,
    u16* __restrict__ wtap, u16* __restrict__ w2b, u16* __restrict__ dwb)
{
    int idx = blockIdx.x * 256 + threadIdx.x;      // < 53248
    if (idx < 36864) {
        int tap = idx >> 12;
        int r = idx & 4095;
        int co = r >> 6, ci = r & 63;
        wtap[idx] = f2bf(ec1w[co * 576 + ci * 9 + tap]);
    } else if (idx < 45056) {
        int r = idx - 36864;
        w2b[r] = f2bf(ec2w[r]);
    } else if (idx < 53248) {
        int r = idx - 45056;
        dwb[r] = f2bf(dw[r]);
    }
}

// ============ Encoder conv 3x3 via shifted MFMA + FiLM + fused 1x1 proj ============
__global__ __launch_bounds__(256) void k_enc_conv3(
    const float* __restrict__ dct, const float* __restrict__ qt,
    const u16* __restrict__ wtap, const float* __restrict__ b1,
    const u16* __restrict__ w2b, const float* __restrict__ eb2,
    float* __restrict__ x)
{
    int h = blockIdx.x & 127, n = blockIdx.x >> 7;
    int tid = threadIdx.x;
    int lane = tid & 63, wv = tid >> 6;
    int la = lane & 15, hi = lane >> 4, kb8 = hi * 8;
    __shared__ u16 smem[3 * 132 * 72];   // 57024 B; conv input, then reused as FiLM tile
    u16 (*inl)[132][72] = reinterpret_cast<u16 (*)[132][72]>(smem);
    u16 (*tl)[72] = reinterpret_cast<u16 (*)[72]>(smem);   // [w(128)][ci(64) pad 72]

    for (int e = tid; e < 384; e += 256) {
        int dh = e >> 7, r = e & 127;
        int ci = r >> 1, wi = (r & 1) * 129;
        inl[dh][wi][ci] = 0;
    }
    #pragma unroll
    for (int dh = 0; dh < 3; ++dh) {
        int hh = h + dh - 1;
        bool ok = (hh >= 0) && (hh < HB);
        for (int it = 0; it < 32; ++it) {
            int e = it * 256 + tid;
            int ci = e >> 7, w = e & 127;
            float v = ok ? dct[((size_t)(n * 64 + ci) * HW) + hh * WB + w] : 0.f;
            inl[dh][w + 1][ci] = f2bf(v);
        }
    }
    __syncthreads();

    f32x4 acc[2][4];
    #pragma unroll
    for (int m = 0; m < 2; ++m)
        #pragma unroll
        for (int nt = 0; nt < 4; ++nt) acc[m][nt] = (f32x4){0.f, 0.f, 0.f, 0.f};

    #pragma unroll
    for (int dh = 0; dh < 3; ++dh) {
        #pragma unroll
        for (int dw = 0; dw < 3; ++dw) {
            #pragma unroll
            for (int kk = 0; kk < 2; ++kk) {
                s16x8 a0 = *(const s16x8*)&inl[dh][wv * 32 + la + dw][kk * 32 + kb8];
                s16x8 a1 = *(const s16x8*)&inl[dh][wv * 32 + 16 + la + dw][kk * 32 + kb8];
                const u16* wb = wtap + (dh * 3 + dw) * 4096 + kk * 32 + kb8;
                #pragma unroll
                for (int nt = 0; nt < 4; ++nt) {
                    s16x8 bf = *(const s16x8*)(wb + (nt * 16 + la) * 64);
                    acc[0][nt] = __builtin_amdgcn_mfma_f32_16x16x32_bf16(a0, bf, acc[0][nt], 0, 0, 0);
                    acc[1][nt] = __builtin_amdgcn_mfma_f32_16x16x32_bf16(a1, bf, acc[1][nt], 0, 0, 0);
                }
            }
        }
    }
    __syncthreads();

    #pragma unroll
    for (int mt = 0; mt < 2; ++mt) {
        #pragma unroll
        for (int nt = 0; nt < 4; ++nt) {
            int co = nt * 16 + la;
            int w0 = wv * 32 + mt * 16 + hi * 4;
            float qv = qt[n * 64 + co];
            float bb = b1[co];
            size_t off = ((size_t)(n * 64 + co) * HW) + h * WB + w0;
            float4 d4 = *reinterpret_cast<const float4*>(dct + off);
            tl[w0 + 0][co] = f2bf(d4.x + qv * (acc[mt][nt][0] + bb));
            tl[w0 + 1][co] = f2bf(d4.y + qv * (acc[mt][nt][1] + bb));
            tl[w0 + 2][co] = f2bf(d4.z + qv * (acc[mt][nt][2] + bb));
            tl[w0 + 3][co] = f2bf(d4.w + qv * (acc[mt][nt][3] + bb));
        }
    }
    __syncthreads();

    f32x4 xa[2][8];
    #pragma unroll
    for (int m = 0; m < 2; ++m)
        #pragma unroll
        for (int j = 0; j < 8; ++j) xa[m][j] = (f32x4){0.f, 0.f, 0.f, 0.f};
    #pragma unroll
    for (int kk = 0; kk < 2; ++kk) {
        s16x8 a0 = *(const s16x8*)&tl[wv * 32 + la][kk * 32 + kb8];
        s16x8 a1 = *(const s16x8*)&tl[wv * 32 + 16 + la][kk * 32 + kb8];
        #pragma unroll
        for (int j = 0; j < 8; ++j) {
            s16x8 bf = *(const s16x8*)(w2b + (j * 16 + la) * 64 + kk * 32 + kb8);
            xa[0][j] = __builtin_amdgcn_mfma_f32_16x16x32_bf16(a0, bf, xa[0][j], 0, 0, 0);
            xa[1][j] = __builtin_amdgcn_mfma_f32_16x16x32_bf16(a1, bf, xa[1][j], 0, 0, 0);
        }
    }
    #pragma unroll
    for (int j = 0; j < 8; ++j) {
        int e = j * 16 + la;
        float be = eb2[e];
        #pragma unroll
        for (int mt = 0; mt < 2; ++mt) {
            int w0 = wv * 32 + mt * 16 + hi * 4;
            size_t pos = (size_t)n * HW + h * WB + w0;
            #pragma unroll
            for (int i = 0; i < 4; ++i)
                x[(pos + i) * EE + e] = xa[mt][j][i] + be;
        }
    }
}

// ============ LN1 + QKV via MFMA: 64 rows/block, 4 M-tiles per B-load ============
__global__ __launch_bounds__(256) void k_qkv3(
    const float* __restrict__ x,
    const float* __restrict__ g, const float* __restrict__ b,
    const u16* __restrict__ wqkvt,
    const float* __restrict__ bq, const float* __restrict__ bk, const float* __restrict__ bv,
    u16* __restrict__ qo, u16* __restrict__ ko, u16* __restrict__ vo)
{
    int pos0 = blockIdx.x * 64;
    int tid = threadIdx.x;
    int lane = tid & 63, wv = tid >> 6;
    __shared__ u16 y0l[64][136];

    // LN1: thread = (row r = tid>>2, 32 cols at c0)
    {
        int r = tid >> 2, c0 = (tid & 3) * 32;
        const float* xr = x + (size_t)(pos0 + r) * EE + c0;
        float xv[32]; float s1 = 0.f, s2 = 0.f;
        #pragma unroll
        for (int i = 0; i < 32; ++i) { xv[i] = xr[i]; s1 += xv[i]; s2 += xv[i] * xv[i]; }
        s1 += __shfl_xor(s1, 1); s2 += __shfl_xor(s2, 1);
        s1 += __shfl_xor(s1, 2); s2 += __shfl_xor(s2, 2);
        float m = s1 * (1.0f / 128.0f);
        float var = s2 * (1.0f / 128.0f) - m * m;
        float rstd = rsqrtf(var + EPSV);
        #pragma unroll
        for (int i = 0; i < 32; ++i)
            y0l[r][c0 + i] = f2bf((xv[i] - m) * rstd * g[c0 + i] + b[c0 + i]);
    }
    __syncthreads();

    f32x4 acc[4][6];
    #pragma unroll
    for (int m = 0; m < 4; ++m)
        #pragma unroll
        for (int j = 0; j < 6; ++j) acc[m][j] = (f32x4){0.f, 0.f, 0.f, 0.f};
    int la = lane & 15, kb = (lane >> 4) << 3;
    #pragma unroll
    for (int kk = 0; kk < 4; ++kk) {
        s16x8 a[4];
        #pragma unroll
        for (int m = 0; m < 4; ++m) a[m] = *(const s16x8*)&y0l[m * 16 + la][kk * 32 + kb];
        #pragma unroll
        for (int j = 0; j < 6; ++j) {
            int nt = wv * 6 + j;
            s16x8 bf = *(const s16x8*)(wqkvt + (size_t)(nt * 16 + la) * 128 + kk * 32 + kb);
            #pragma unroll
            for (int m = 0; m < 4; ++m)
                acc[m][j] = __builtin_amdgcn_mfma_f32_16x16x32_bf16(a[m], bf, acc[m][j], 0, 0, 0);
        }
    }
    #pragma unroll
    for (int j = 0; j < 6; ++j) {
        int nt = wv * 6 + j;
        int mat = nt >> 3;
        int ncol = (nt & 7) * 16 + la;
        float bias = (mat == 0) ? bq[ncol] : (mat == 1) ? bk[ncol] : bv[ncol];
        u16* dst = (mat == 0) ? qo : (mat == 1) ? ko : vo;
        #pragma unroll
        for (int m = 0; m < 4; ++m) {
            #pragma unroll
            for (int i = 0; i < 4; ++i) {
                int row = m * 16 + ((lane >> 4) << 2) + i;
                dst[(size_t)(pos0 + row) * EE + ncol] = f2bf(acc[m][j][i] + bias);
            }
        }
    }
}

// ============ 7x7 sliding-window attention via masked MFMA ============
__global__ __launch_bounds__(256) void k_attn2(
    const u16* __restrict__ q, const u16* __restrict__ k,
    const u16* __restrict__ v, const float* __restrict__ rb,
    float* __restrict__ y2)
{
    int bid = blockIdx.x;
    int hd = bid & 3;
    int wg = (bid >> 2) & 7;
    int hg = (bid >> 5) & 31;
    int n = bid >> 10;
    int h0 = hg * 4, w0 = wg * 16;
    int tid = threadIdx.x;
    int lane = tid & 63, wv = tid >> 6;
    int la = lane & 15, hi = lane >> 4, kb8 = hi * 8;

    __shared__ u16 ksl[224][40];
    __shared__ u16 vtl[32][232];
    __shared__ u16 psl[64][232];
    __shared__ float rbl[PP];

    if (tid < PP) rbl[tid] = rb[hd * PP + tid];

    for (int c = tid; c < 896; c += 256) {
        int kpos = c >> 2, qtr = c & 3;
        int kr = kpos / 22, kc = kpos - kr * 22;
        int hh = h0 + kr - 3, ww = w0 + kc - 3;
        s16x8 kvv = (s16x8){0,0,0,0,0,0,0,0};
        s16x8 vvv = (s16x8){0,0,0,0,0,0,0,0};
        if (kpos < 220 && hh >= 0 && hh < HB && ww >= 0 && ww < WB) {
            size_t base = ((size_t)(n * HW + hh * WB + ww)) * EE + hd * 32 + qtr * 8;
            kvv = *(const s16x8*)(k + base);
            vvv = *(const s16x8*)(v + base);
        }
        *(s16x8*)&ksl[kpos][qtr * 8] = kvv;
        #pragma unroll
        for (int d = 0; d < 8; ++d) vtl[qtr * 8 + d][kpos] = (u16)vvv[d];
    }
    __syncthreads();

    s16x8 qf = *(const s16x8*)(q + ((size_t)(n * HW + (h0 + wv) * WB + w0 + la)) * EE + hd * 32 + kb8);

    f32x4 s[14];
    #pragma unroll
    for (int j = 0; j < 14; ++j) s[j] = (f32x4){0.f, 0.f, 0.f, 0.f};
    #pragma unroll
    for (int j = 0; j < 14; ++j) {
        s16x8 bf = *(const s16x8*)&ksl[j * 16 + la][kb8];
        s[j] = __builtin_amdgcn_mfma_f32_16x16x32_bf16(qf, bf, s[j], 0, 0, 0);
    }

    const float scale = 0.088388347648318447f; // 1/sqrt(128)
    #pragma unroll
    for (int j = 0; j < 14; ++j) {
        int kpos = j * 16 + la;
        int kr = kpos / 22, kc = kpos - kr * 22;
        int di = kr - wv;
        bool rowok = (kpos < 220) && (di >= 0) && (di <= 6);
        #pragma unroll
        for (int i = 0; i < 4; ++i) {
            int qc = hi * 4 + i;
            int dj = kc - qc;
            bool ok = rowok && (dj >= 0) && (dj <= 6);
            s[j][i] = ok ? (s[j][i] * scale + rbl[di * 7 + dj]) : -1e30f;
        }
    }
    float mx[4] = {-1e30f, -1e30f, -1e30f, -1e30f};
    #pragma unroll
    for (int j = 0; j < 14; ++j)
        #pragma unroll
        for (int i = 0; i < 4; ++i) mx[i] = fmaxf(mx[i], s[j][i]);
    #pragma unroll
    for (int off = 1; off < 16; off <<= 1)
        #pragma unroll
        for (int i = 0; i < 4; ++i) mx[i] = fmaxf(mx[i], __shfl_xor(mx[i], off));
    float sum[4] = {0.f, 0.f, 0.f, 0.f};
    #pragma unroll
    for (int j = 0; j < 14; ++j)
        #pragma unroll
        for (int i = 0; i < 4; ++i) {
            float e_ = __expf(s[j][i] - mx[i]);
            s[j][i] = e_; sum[i] += e_;
        }
    #pragma unroll
    for (int off = 1; off < 16; off <<= 1)
        #pragma unroll
        for (int i = 0; i < 4; ++i) sum[i] += __shfl_xor(sum[i], off);
    float inv[4];
    #pragma unroll
    for (int i = 0; i < 4; ++i) inv[i] = 1.0f / sum[i];
    #pragma unroll
    for (int j = 0; j < 14; ++j)
        #pragma unroll
        for (int i = 0; i < 4; ++i)
            psl[wv * 16 + hi * 4 + i][j * 16 + la] = f2bf(s[j][i] * inv[i]);

    f32x4 o[2];
    o[0] = (f32x4){0.f, 0.f, 0.f, 0.f};
    o[1] = (f32x4){0.f, 0.f, 0.f, 0.f};
    #pragma unroll
    for (int kk = 0; kk < 7; ++kk) {
        s16x8 pa = *(const s16x8*)&psl[wv * 16 + la][kk * 32 + kb8];
        #pragma unroll
        for (int nt = 0; nt < 2; ++nt) {
            s16x8 vb = *(const s16x8*)&vtl[nt * 16 + la][kk * 32 + kb8];
            o[nt] = __builtin_amdgcn_mfma_f32_16x16x32_bf16(pa, vb, o[nt], 0, 0, 0);
        }
    }
    #pragma unroll
    for (int nt = 0; nt < 2; ++nt) {
        #pragma unroll
        for (int i = 0; i < 4; ++i) {
            int qc = hi * 4 + i;
            y2[((size_t)(n * HW + (h0 + wv) * WB + w0 + qc)) * EE + hd * 32 + nt * 16 + la] = o[nt][i];
        }
    }
}

// ============ LN2 + FF via MFMA, K-split pipelined halves (25.6KB LDS) ============
__global__ __launch_bounds__(256) void k_ff3(
    float* __restrict__ x, const float* __restrict__ y2,
    const float* __restrict__ g, const float* __restrict__ b,
    const u16* __restrict__ w1t, const float* __restrict__ b1,
    const u16* __restrict__ w2t, const float* __restrict__ b2)
{
    int pos0 = blockIdx.x * 32;
    int tid = threadIdx.x;
    int lane = tid & 63, wv = tid >> 6;
    __shared__ u16 y3l[32][136];
    __shared__ u16 hl[32][264];   // one 256-col half of h at a time

    {
        int r = tid >> 3, c0 = (tid & 7) * 16;
        const float* xr = x + (size_t)(pos0 + r) * EE + c0;
        const float* yr = y2 + (size_t)(pos0 + r) * EE + c0;
        float tv[16]; float s1 = 0.f, s2 = 0.f;
        #pragma unroll
        for (int i = 0; i < 16; ++i) {
            tv[i] = xr[i] + yr[i];
            s1 += tv[i]; s2 += tv[i] * tv[i];
        }
        #pragma unroll
        for (int off = 1; off < 8; off <<= 1) { s1 += __shfl_xor(s1, off); s2 += __shfl_xor(s2, off); }
        float m = s1 * (1.0f / 128.0f);
        float var = s2 * (1.0f / 128.0f) - m * m;
        float rstd = rsqrtf(var + EPSV);
        #pragma unroll
        for (int i = 0; i < 16; ++i)
            y3l[r][c0 + i] = f2bf((tv[i] - m) * rstd * g[c0 + i] + b[c0 + i]);
    }
    __syncthreads();

    int la = lane & 15, kb = (lane >> 4) << 3;
    f32x4 acc2[2][2];
    #pragma unroll
    for (int m = 0; m < 2; ++m)
        #pragma unroll
        for (int j = 0; j < 2; ++j) acc2[m][j] = (f32x4){0.f, 0.f, 0.f, 0.f};

    #pragma unroll
    for (int half = 0; half < 2; ++half) {
        // GEMM1 half: 256 DFF cols, wave covers 64
        f32x4 acc[2][4];
        #pragma unroll
        for (int m = 0; m < 2; ++m)
            #pragma unroll
            for (int j = 0; j < 4; ++j) acc[m][j] = (f32x4){0.f, 0.f, 0.f, 0.f};
        int n0 = half * 256 + wv * 64;
        #pragma unroll
        for (int kk = 0; kk < 4; ++kk) {
            s16x8 a0 = *(const s16x8*)&y3l[la][kk * 32 + kb];
            s16x8 a1 = *(const s16x8*)&y3l[16 + la][kk * 32 + kb];
            #pragma unroll
            for (int j = 0; j < 4; ++j) {
                s16x8 bf = *(const s16x8*)(w1t + (size_t)(n0 + j * 16 + la) * 128 + kk * 32 + kb);
                acc[0][j] = __builtin_amdgcn_mfma_f32_16x16x32_bf16(a0, bf, acc[0][j], 0, 0, 0);
                acc[1][j] = __builtin_amdgcn_mfma_f32_16x16x32_bf16(a1, bf, acc[1][j], 0, 0, 0);
            }
        }
        // bias + gelu -> hl (local col)
        #pragma unroll
        for (int j = 0; j < 4; ++j) {
            int gcol = n0 + j * 16 + la;
            int lcol = wv * 64 + j * 16 + la;
            float bb = b1[gcol];
            #pragma unroll
            for (int m = 0; m < 2; ++m) {
                #pragma unroll
                for (int i = 0; i < 4; ++i) {
                    int row = m * 16 + ((lane >> 4) << 2) + i;
                    hl[row][lcol] = f2bf(gelu_f(acc[m][j][i] + bb));
                }
            }
        }
        __syncthreads();
        // GEMM2 partial: K = this half's 256
        int n0b = wv * 32;
        #pragma unroll
        for (int kk = 0; kk < 8; ++kk) {
            s16x8 a0 = *(const s16x8*)&hl[la][kk * 32 + kb];
            s16x8 a1 = *(const s16x8*)&hl[16 + la][kk * 32 + kb];
            int gkk = half * 8 + kk;
            #pragma unroll
            for (int j = 0; j < 2; ++j) {
                s16x8 bf = *(const s16x8*)(w2t + (size_t)(n0b + j * 16 + la) * 512 + gkk * 32 + kb);
                acc2[0][j] = __builtin_amdgcn_mfma_f32_16x16x32_bf16(a0, bf, acc2[0][j], 0, 0, 0);
                acc2[1][j] = __builtin_amdgcn_mfma_f32_16x16x32_bf16(a1, bf, acc2[1][j], 0, 0, 0);
            }
        }
        __syncthreads();   // hl safe to overwrite next half
    }

    #pragma unroll
    for (int j = 0; j < 2; ++j) {
        int col = wv * 32 + j * 16 + la;
        float bb = b2[col];
        #pragma unroll
        for (int m = 0; m < 2; ++m) {
            #pragma unroll
            for (int i = 0; i < 4; ++i) {
                int row = m * 16 + ((lane >> 4) << 2) + i;
                size_t grow = (size_t)(pos0 + row) * EE + col;
                x[grow] = y2[grow] + acc2[m][j][i] + bb;
            }
        }
    }
}

// ============ Decoder via MFMA ============
__global__ __launch_bounds__(256) void k_dec2(
    const float* __restrict__ x, const float* __restrict__ dct,
    const float* __restrict__ qt, const u16* __restrict__ dwb,
    const float* __restrict__ bd, float* __restrict__ out)
{
    int pos0 = blockIdx.x * 64;
    int n = pos0 >> 14;
    int hw0 = pos0 & 16383;
    int tid = threadIdx.x;
    int lane = tid & 63, wv = tid >> 6;
    int la = lane & 15, hi = lane >> 4, kb8 = hi * 8;
    __shared__ u16 al[64][136];

    for (int it = 0; it < 32; ++it) {
        int idx = it * 256 + tid;
        int r = idx >> 7, c = idx & 127;
        al[r][c] = f2bf(x[(size_t)(pos0 + r) * EE + c]);
    }
    __syncthreads();

    f32x4 acc[4];
    #pragma unroll
    for (int m = 0; m < 4; ++m) acc[m] = (f32x4){0.f, 0.f, 0.f, 0.f};
    #pragma unroll
    for (int kk = 0; kk < 4; ++kk) {
        s16x8 bf = *(const s16x8*)(dwb + (wv * 16 + la) * 128 + kk * 32 + kb8);
        #pragma unroll
        for (int m = 0; m < 4; ++m) {
            s16x8 a = *(const s16x8*)&al[m * 16 + la][kk * 32 + kb8];
            acc[m] = __builtin_amdgcn_mfma_f32_16x16x32_bf16(a, bf, acc[m], 0, 0, 0);
        }
    }
    int co = wv * 16 + la;
    float qv = qt[n * 64 + co];
    float bb = bd[co];
    #pragma unroll
    for (int m = 0; m < 4; ++m) {
        int p = m * 16 + hi * 4;
        size_t off = ((size_t)(n * 64 + co)) * HW + hw0 + p;
        float4 d4 = *reinterpret_cast<const float4*>(dct + off);
        float4 r;
        r.x = d4.x + (acc[m][0] + bb) * qv;
        r.y = d4.y + (acc[m][1] + bb) * qv;
        r.z = d4.z + (acc[m][2] + bb) * qv;
        r.w = d4.w + (acc[m][3] + bb) * qv;
        *reinterpret_cast<float4*>(out + off) = r;
    }
}

extern "C" void kernel_launch(void* const* d_in, const int* in_sizes, int n_in,
                              void* d_out, int out_size, void* d_ws, size_t ws_size,
                              hipStream_t stream) {
    const float* dct  = (const float*)d_in[0];
    const float* qt   = (const float*)d_in[1];
    const float* ec1w = (const float*)d_in[2];
    const float* ec1b = (const float*)d_in[3];
    const float* ec2w = (const float*)d_in[4];
    const float* ec2b = (const float*)d_in[5];
    const float* ln1g = (const float*)d_in[6];
    const float* ln1b = (const float*)d_in[7];
    const float* qw   = (const float*)d_in[8];
    const float* qb   = (const float*)d_in[9];
    const float* kw   = (const float*)d_in[10];
    const float* kb   = (const float*)d_in[11];
    const float* vw   = (const float*)d_in[12];
    const float* vb   = (const float*)d_in[13];
    const float* rb   = (const float*)d_in[14];
    const float* ln2g = (const float*)d_in[15];
    const float* ln2b = (const float*)d_in[16];
    const float* fw1  = (const float*)d_in[17];
    const float* fb1  = (const float*)d_in[18];
    const float* fw2  = (const float*)d_in[19];
    const float* fb2  = (const float*)d_in[20];
    const float* dw   = (const float*)d_in[21];
    const float* db   = (const float*)d_in[22];

    char* ws = (char*)d_ws;
    float* xbuf  = (float*)ws;                         // 67108864 B
    float* y2buf = (float*)(ws + 67108864);            // 67108864 B
    u16*   qbuf  = (u16*)(ws + 134217728);             // 33554432 B
    u16*   kbuf  = (u16*)(ws + 167772160);             // 33554432 B
    u16*   vbuf  = (u16*)(ws + 201326592);             // 33554432 B
    size_t woff = 234881024;
    u16* wqkvt = (u16*)(ws + woff);                    // 393216 B
    u16* w1t   = (u16*)(ws + woff + 393216);           // 524288 B
    u16* w2t   = (u16*)(ws + woff + 917504);           // 524288 B
    u16* wtap  = (u16*)(ws + woff + 1441792);          // 73728 B
    u16* w2b   = (u16*)(ws + woff + 1515520);          // 16384 B
    u16* dwb   = (u16*)(ws + woff + 1531904);          // 16384 B

    k_prep_qkvff<<<dim3(2816), dim3(256), 0, stream>>>(qw, kw, vw, fw1, fw2, wqkvt, w1t, w2t);
    k_prep_conv<<<dim3(208), dim3(256), 0, stream>>>(ec1w, ec2w, dw, wtap, w2b, dwb);

    k_enc_conv3<<<dim3(NB * HB), dim3(256), 0, stream>>>(dct, qt, wtap, ec1b, w2b, ec2b, xbuf);
    for (int l = 0; l < NLAY; ++l) {
        k_qkv3<<<dim3(NPOS / 64), dim3(256), 0, stream>>>(
            xbuf, ln1g + l * EE, ln1b + l * EE,
            wqkvt + l * 49152,
            qb + l * EE, kb + l * EE, vb + l * EE,
            qbuf, kbuf, vbuf);
        k_attn2<<<dim3(NB * 32 * 8 * 4), dim3(256), 0, stream>>>(
            qbuf, kbuf, vbuf, rb + l * NHD * PP, y2buf);
        k_ff3<<<dim3(NPOS / 32), dim3(256), 0, stream>>>(
            xbuf, y2buf, ln2g + l * EE, ln2b + l * EE,
            w1t + l * 65536, fb1 + l * DFF,
            w2t + l * 65536, fb2 + l * EE);
    }
    k_dec2<<<dim3(NPOS / 64), dim3(256), 0, stream>>>(
        xbuf, dct, qt, dwb, db, (float*)d_out);
}

// Round 9
// 1455.705 us; speedup vs baseline: 1.1977x; 1.1977x over previous
//
#include <hip/hip_runtime.h>
#include <math.h>

#define NB 8
#define CDCT 64
#define HB 128
#define WB 128
#define EE 128
#define NHD 4
#define KS 7
#define PP 49
#define DFF 512
#define NLAY 4
#define HW (HB*WB)          // 16384
#define NPOS (NB*HB*WB)     // 131072
#define EPSV 1e-5f

typedef unsigned short u16;
typedef float f32x4 __attribute__((ext_vector_type(4)));
typedef short s16x8 __attribute__((ext_vector_type(8)));

__device__ __forceinline__ float bf2f(u16 u) {
    union { unsigned int i; float f; } c; c.i = ((unsigned int)u) << 16; return c.f;
}
__device__ __forceinline__ u16 f2bf(float f) {
    union { float f; unsigned int i; } c; c.f = f;
    unsigned int x = c.i;
    return (u16)((x + 0x7fffu + ((x >> 16) & 1u)) >> 16);
}
// GELU: sigmoid form of the tanh approximation (<=0.003 abs dev from erf-GELU,
// below bf16 rounding of h).
__device__ __forceinline__ float gelu_f(float x) {
    float t2 = 1.5957691216057308f * (x + 0.044715f * x * x * x);
    return x / (1.0f + __expf(-t2));
}

// ============ prep: transpose+convert transformer weights to bf16 ============
__global__ __launch_bounds__(256) void k_prep_qkvff(
    const float* __restrict__ qw, const float* __restrict__ kw, const float* __restrict__ vw,
    const float* __restrict__ fw1, const float* __restrict__ fw2,
    u16* __restrict__ wqkvt, u16* __restrict__ w1t, u16* __restrict__ w2t)
{
    int idx = blockIdx.x * 256 + threadIdx.x;      // < 720896
    int l = idx / 180224;
    int rem = idx - l * 180224;
    if (rem < 49152) {
        int n = rem >> 7, k2 = rem & 127;
        int mat = n >> 7, c = n & 127;
        const float* src = (mat == 0) ? qw : (mat == 1) ? kw : vw;
        wqkvt[l * 49152 + rem] = f2bf(src[l * 16384 + k2 * 128 + c]);
    } else if (rem < 114688) {
        int r2 = rem - 49152;
        int j = r2 >> 7, i = r2 & 127;
        w1t[l * 65536 + r2] = f2bf(fw1[l * 65536 + i * 512 + j]);
    } else {
        int r3 = rem - 114688;
        int e = r3 >> 9, d = r3 & 511;
        w2t[l * 65536 + r3] = f2bf(fw2[l * 65536 + d * 128 + e]);
    }
}

// prep conv/enc-proj/decoder weights
__global__ __launch_bounds__(256) void k_prep_conv(
    const float* __restrict__ ec1w, const float* __restrict__ ec2w,
    const float* __restrict__ dw,
    u16* __restrict__ wtap, u16* __restrict__ w2b, u16* __restrict__ dwb)
{
    int idx = blockIdx.x * 256 + threadIdx.x;      // < 53248
    if (idx < 36864) {
        int tap = idx >> 12;
        int r = idx & 4095;
        int co = r >> 6, ci = r & 63;
        wtap[idx] = f2bf(ec1w[co * 576 + ci * 9 + tap]);
    } else if (idx < 45056) {
        int r = idx - 36864;
        w2b[r] = f2bf(ec2w[r]);
    } else if (idx < 53248) {
        int r = idx - 45056;
        dwb[r] = f2bf(dw[r]);
    }
}

// ============ Encoder conv 3x3 via shifted MFMA + FiLM + fused 1x1 proj ============
__global__ __launch_bounds__(256) void k_enc_conv3(
    const float* __restrict__ dct, const float* __restrict__ qt,
    const u16* __restrict__ wtap, const float* __restrict__ b1,
    const u16* __restrict__ w2b, const float* __restrict__ eb2,
    float* __restrict__ x)
{
    int h = blockIdx.x & 127, n = blockIdx.x >> 7;
    int tid = threadIdx.x;
    int lane = tid & 63, wv = tid >> 6;
    int la = lane & 15, hi = lane >> 4, kb8 = hi * 8;
    __shared__ u16 smem[3 * 132 * 72];
    u16 (*inl)[132][72] = reinterpret_cast<u16 (*)[132][72]>(smem);
    u16 (*tl)[72] = reinterpret_cast<u16 (*)[72]>(smem);

    for (int e = tid; e < 384; e += 256) {
        int dh = e >> 7, r = e & 127;
        int ci = r >> 1, wi = (r & 1) * 129;
        inl[dh][wi][ci] = 0;
    }
    #pragma unroll
    for (int dh = 0; dh < 3; ++dh) {
        int hh = h + dh - 1;
        bool ok = (hh >= 0) && (hh < HB);
        for (int it = 0; it < 32; ++it) {
            int e = it * 256 + tid;
            int ci = e >> 7, w = e & 127;
            float v = ok ? dct[((size_t)(n * 64 + ci) * HW) + hh * WB + w] : 0.f;
            inl[dh][w + 1][ci] = f2bf(v);
        }
    }
    __syncthreads();

    f32x4 acc[2][4];
    #pragma unroll
    for (int m = 0; m < 2; ++m)
        #pragma unroll
        for (int nt = 0; nt < 4; ++nt) acc[m][nt] = (f32x4){0.f, 0.f, 0.f, 0.f};

    #pragma unroll
    for (int dh = 0; dh < 3; ++dh) {
        #pragma unroll
        for (int dw = 0; dw < 3; ++dw) {
            #pragma unroll
            for (int kk = 0; kk < 2; ++kk) {
                s16x8 a0 = *(const s16x8*)&inl[dh][wv * 32 + la + dw][kk * 32 + kb8];
                s16x8 a1 = *(const s16x8*)&inl[dh][wv * 32 + 16 + la + dw][kk * 32 + kb8];
                const u16* wb = wtap + (dh * 3 + dw) * 4096 + kk * 32 + kb8;
                #pragma unroll
                for (int nt = 0; nt < 4; ++nt) {
                    s16x8 bf = *(const s16x8*)(wb + (nt * 16 + la) * 64);
                    acc[0][nt] = __builtin_amdgcn_mfma_f32_16x16x32_bf16(a0, bf, acc[0][nt], 0, 0, 0);
                    acc[1][nt] = __builtin_amdgcn_mfma_f32_16x16x32_bf16(a1, bf, acc[1][nt], 0, 0, 0);
                }
            }
        }
    }
    __syncthreads();

    #pragma unroll
    for (int mt = 0; mt < 2; ++mt) {
        #pragma unroll
        for (int nt = 0; nt < 4; ++nt) {
            int co = nt * 16 + la;
            int w0 = wv * 32 + mt * 16 + hi * 4;
            float qv = qt[n * 64 + co];
            float bb = b1[co];
            size_t off = ((size_t)(n * 64 + co) * HW) + h * WB + w0;
            float4 d4 = *reinterpret_cast<const float4*>(dct + off);
            tl[w0 + 0][co] = f2bf(d4.x + qv * (acc[mt][nt][0] + bb));
            tl[w0 + 1][co] = f2bf(d4.y + qv * (acc[mt][nt][1] + bb));
            tl[w0 + 2][co] = f2bf(d4.z + qv * (acc[mt][nt][2] + bb));
            tl[w0 + 3][co] = f2bf(d4.w + qv * (acc[mt][nt][3] + bb));
        }
    }
    __syncthreads();

    f32x4 xa[2][8];
    #pragma unroll
    for (int m = 0; m < 2; ++m)
        #pragma unroll
        for (int j = 0; j < 8; ++j) xa[m][j] = (f32x4){0.f, 0.f, 0.f, 0.f};
    #pragma unroll
    for (int kk = 0; kk < 2; ++kk) {
        s16x8 a0 = *(const s16x8*)&tl[wv * 32 + la][kk * 32 + kb8];
        s16x8 a1 = *(const s16x8*)&tl[wv * 32 + 16 + la][kk * 32 + kb8];
        #pragma unroll
        for (int j = 0; j < 8; ++j) {
            s16x8 bf = *(const s16x8*)(w2b + (j * 16 + la) * 64 + kk * 32 + kb8);
            xa[0][j] = __builtin_amdgcn_mfma_f32_16x16x32_bf16(a0, bf, xa[0][j], 0, 0, 0);
            xa[1][j] = __builtin_amdgcn_mfma_f32_16x16x32_bf16(a1, bf, xa[1][j], 0, 0, 0);
        }
    }
    #pragma unroll
    for (int j = 0; j < 8; ++j) {
        int e = j * 16 + la;
        float be = eb2[e];
        #pragma unroll
        for (int mt = 0; mt < 2; ++mt) {
            int w0 = wv * 32 + mt * 16 + hi * 4;
            size_t pos = (size_t)n * HW + h * WB + w0;
            #pragma unroll
            for (int i = 0; i < 4; ++i)
                x[(pos + i) * EE + e] = xa[mt][j][i] + be;
        }
    }
}

// ============ LN1 + QKV via MFMA: 64 rows/block ============
__global__ __launch_bounds__(256) void k_qkv3(
    const float* __restrict__ x,
    const float* __restrict__ g, const float* __restrict__ b,
    const u16* __restrict__ wqkvt,
    const float* __restrict__ bq, const float* __restrict__ bk, const float* __restrict__ bv,
    u16* __restrict__ qo, u16* __restrict__ ko, u16* __restrict__ vo)
{
    int pos0 = blockIdx.x * 64;
    int tid = threadIdx.x;
    int lane = tid & 63, wv = tid >> 6;
    __shared__ u16 y0l[64][136];

    {
        int r = tid >> 2, c0 = (tid & 3) * 32;
        const float* xr = x + (size_t)(pos0 + r) * EE + c0;
        float xv[32]; float s1 = 0.f, s2 = 0.f;
        #pragma unroll
        for (int i = 0; i < 32; ++i) { xv[i] = xr[i]; s1 += xv[i]; s2 += xv[i] * xv[i]; }
        s1 += __shfl_xor(s1, 1); s2 += __shfl_xor(s2, 1);
        s1 += __shfl_xor(s1, 2); s2 += __shfl_xor(s2, 2);
        float m = s1 * (1.0f / 128.0f);
        float var = s2 * (1.0f / 128.0f) - m * m;
        float rstd = rsqrtf(var + EPSV);
        #pragma unroll
        for (int i = 0; i < 32; ++i)
            y0l[r][c0 + i] = f2bf((xv[i] - m) * rstd * g[c0 + i] + b[c0 + i]);
    }
    __syncthreads();

    f32x4 acc[4][6];
    #pragma unroll
    for (int m = 0; m < 4; ++m)
        #pragma unroll
        for (int j = 0; j < 6; ++j) acc[m][j] = (f32x4){0.f, 0.f, 0.f, 0.f};
    int la = lane & 15, kb = (lane >> 4) << 3;
    #pragma unroll
    for (int kk = 0; kk < 4; ++kk) {
        s16x8 a[4];
        #pragma unroll
        for (int m = 0; m < 4; ++m) a[m] = *(const s16x8*)&y0l[m * 16 + la][kk * 32 + kb];
        #pragma unroll
        for (int j = 0; j < 6; ++j) {
            int nt = wv * 6 + j;
            s16x8 bf = *(const s16x8*)(wqkvt + (size_t)(nt * 16 + la) * 128 + kk * 32 + kb);
            #pragma unroll
            for (int m = 0; m < 4; ++m)
                acc[m][j] = __builtin_amdgcn_mfma_f32_16x16x32_bf16(a[m], bf, acc[m][j], 0, 0, 0);
        }
    }
    #pragma unroll
    for (int j = 0; j < 6; ++j) {
        int nt = wv * 6 + j;
        int mat = nt >> 3;
        int ncol = (nt & 7) * 16 + la;
        float bias = (mat == 0) ? bq[ncol] : (mat == 1) ? bk[ncol] : bv[ncol];
        u16* dst = (mat == 0) ? qo : (mat == 1) ? ko : vo;
        #pragma unroll
        for (int m = 0; m < 4; ++m) {
            #pragma unroll
            for (int i = 0; i < 4; ++i) {
                int row = m * 16 + ((lane >> 4) << 2) + i;
                dst[(size_t)(pos0 + row) * EE + ncol] = f2bf(acc[m][j][i] + bias);
            }
        }
    }
}

// ============ 7x7 sliding-window attention via masked MFMA (psl K-split, 50KB LDS) ============
__global__ __launch_bounds__(256) void k_attn3(
    const u16* __restrict__ q, const u16* __restrict__ k,
    const u16* __restrict__ v, const float* __restrict__ rb,
    float* __restrict__ y2)
{
    int bid = blockIdx.x;
    int hd = bid & 3;
    int wg = (bid >> 2) & 7;
    int hg = (bid >> 5) & 31;
    int n = bid >> 10;
    int h0 = hg * 4, w0 = wg * 16;
    int tid = threadIdx.x;
    int lane = tid & 63, wv = tid >> 6;
    int la = lane & 15, hi = lane >> 4, kb8 = hi * 8;

    __shared__ u16 ksl[224][40];    // 17920 B
    __shared__ u16 vtl[32][232];    // 14848 B
    __shared__ u16 psl[64][136];    // 17408 B (one 128-kpos half at a time; wave-private rows)
    __shared__ float rbl[PP];

    if (tid < PP) rbl[tid] = rb[hd * PP + tid];

    for (int c = tid; c < 896; c += 256) {
        int kpos = c >> 2, qtr = c & 3;
        int kr = kpos / 22, kc = kpos - kr * 22;
        int hh = h0 + kr - 3, ww = w0 + kc - 3;
        s16x8 kvv = (s16x8){0,0,0,0,0,0,0,0};
        s16x8 vvv = (s16x8){0,0,0,0,0,0,0,0};
        if (kpos < 220 && hh >= 0 && hh < HB && ww >= 0 && ww < WB) {
            size_t base = ((size_t)(n * HW + hh * WB + ww)) * EE + hd * 32 + qtr * 8;
            kvv = *(const s16x8*)(k + base);
            vvv = *(const s16x8*)(v + base);
        }
        *(s16x8*)&ksl[kpos][qtr * 8] = kvv;
        #pragma unroll
        for (int d = 0; d < 8; ++d) vtl[qtr * 8 + d][kpos] = (u16)vvv[d];
    }
    __syncthreads();

    s16x8 qf = *(const s16x8*)(q + ((size_t)(n * HW + (h0 + wv) * WB + w0 + la)) * EE + hd * 32 + kb8);

    f32x4 s[14];
    #pragma unroll
    for (int j = 0; j < 14; ++j) s[j] = (f32x4){0.f, 0.f, 0.f, 0.f};
    #pragma unroll
    for (int j = 0; j < 14; ++j) {
        s16x8 bf = *(const s16x8*)&ksl[j * 16 + la][kb8];
        s[j] = __builtin_amdgcn_mfma_f32_16x16x32_bf16(qf, bf, s[j], 0, 0, 0);
    }

    const float scale = 0.088388347648318447f; // 1/sqrt(128)
    #pragma unroll
    for (int j = 0; j < 14; ++j) {
        int kpos = j * 16 + la;
        int kr = kpos / 22, kc = kpos - kr * 22;
        int di = kr - wv;
        bool rowok = (kpos < 220) && (di >= 0) && (di <= 6);
        #pragma unroll
        for (int i = 0; i < 4; ++i) {
            int qc = hi * 4 + i;
            int dj = kc - qc;
            bool ok = rowok && (dj >= 0) && (dj <= 6);
            s[j][i] = ok ? (s[j][i] * scale + rbl[di * 7 + dj]) : -1e30f;
        }
    }
    float mx[4] = {-1e30f, -1e30f, -1e30f, -1e30f};
    #pragma unroll
    for (int j = 0; j < 14; ++j)
        #pragma unroll
        for (int i = 0; i < 4; ++i) mx[i] = fmaxf(mx[i], s[j][i]);
    #pragma unroll
    for (int off = 1; off < 16; off <<= 1)
        #pragma unroll
        for (int i = 0; i < 4; ++i) mx[i] = fmaxf(mx[i], __shfl_xor(mx[i], off));
    float sum[4] = {0.f, 0.f, 0.f, 0.f};
    #pragma unroll
    for (int j = 0; j < 14; ++j)
        #pragma unroll
        for (int i = 0; i < 4; ++i) {
            float e_ = __expf(s[j][i] - mx[i]);
            s[j][i] = e_; sum[i] += e_;
        }
    #pragma unroll
    for (int off = 1; off < 16; off <<= 1)
        #pragma unroll
        for (int i = 0; i < 4; ++i) sum[i] += __shfl_xor(sum[i], off);
    float inv[4];
    #pragma unroll
    for (int i = 0; i < 4; ++i) inv[i] = 1.0f / sum[i];

    f32x4 o[2];
    o[0] = (f32x4){0.f, 0.f, 0.f, 0.f};
    o[1] = (f32x4){0.f, 0.f, 0.f, 0.f};

    // half 1: kpos 0..127 (j=0..7)  — psl rows are wave-private, no barrier needed
    #pragma unroll
    for (int j = 0; j < 8; ++j)
        #pragma unroll
        for (int i = 0; i < 4; ++i)
            psl[wv * 16 + hi * 4 + i][j * 16 + la] = f2bf(s[j][i] * inv[i]);
    #pragma unroll
    for (int kk = 0; kk < 4; ++kk) {
        s16x8 pa = *(const s16x8*)&psl[wv * 16 + la][kk * 32 + kb8];
        #pragma unroll
        for (int nt = 0; nt < 2; ++nt) {
            s16x8 vb = *(const s16x8*)&vtl[nt * 16 + la][kk * 32 + kb8];
            o[nt] = __builtin_amdgcn_mfma_f32_16x16x32_bf16(pa, vb, o[nt], 0, 0, 0);
        }
    }
    // half 2: kpos 128..223 (j=8..13)
    #pragma unroll
    for (int j = 8; j < 14; ++j)
        #pragma unroll
        for (int i = 0; i < 4; ++i)
            psl[wv * 16 + hi * 4 + i][(j - 8) * 16 + la] = f2bf(s[j][i] * inv[i]);
    #pragma unroll
    for (int kk = 0; kk < 3; ++kk) {
        s16x8 pa = *(const s16x8*)&psl[wv * 16 + la][kk * 32 + kb8];
        #pragma unroll
        for (int nt = 0; nt < 2; ++nt) {
            s16x8 vb = *(const s16x8*)&vtl[nt * 16 + la][128 + kk * 32 + kb8];
            o[nt] = __builtin_amdgcn_mfma_f32_16x16x32_bf16(pa, vb, o[nt], 0, 0, 0);
        }
    }

    #pragma unroll
    for (int nt = 0; nt < 2; ++nt) {
        #pragma unroll
        for (int i = 0; i < 4; ++i) {
            int qc = hi * 4 + i;
            y2[((size_t)(n * HW + (h0 + wv) * WB + w0 + qc)) * EE + hd * 32 + nt * 16 + la] = o[nt][i];
        }
    }
}

// ============ LN2 + FF via MFMA: M=64/block, K-split halves, 4 MFMA per B-load ============
__global__ __launch_bounds__(256) void k_ff4(
    float* __restrict__ x, const float* __restrict__ y2,
    const float* __restrict__ g, const float* __restrict__ b,
    const u16* __restrict__ w1t, const float* __restrict__ b1,
    const u16* __restrict__ w2t, const float* __restrict__ b2)
{
    int pos0 = blockIdx.x * 64;
    int tid = threadIdx.x;
    int lane = tid & 63, wv = tid >> 6;
    int la = lane & 15, hi = lane >> 4, kb = hi * 8;
    __shared__ u16 y3l[64][136];   // 17408 B
    __shared__ u16 hl[64][264];    // 33792 B (one 256-col half of h)

    // LN2 on tv = x + y2: r = tid>>2 (64 rows), 32 cols each
    {
        int r = tid >> 2, c0 = (tid & 3) * 32;
        const float* xr = x + (size_t)(pos0 + r) * EE + c0;
        const float* yr = y2 + (size_t)(pos0 + r) * EE + c0;
        float tv[32]; float s1 = 0.f, s2 = 0.f;
        #pragma unroll
        for (int i = 0; i < 32; ++i) {
            tv[i] = xr[i] + yr[i];
            s1 += tv[i]; s2 += tv[i] * tv[i];
        }
        s1 += __shfl_xor(s1, 1); s2 += __shfl_xor(s2, 1);
        s1 += __shfl_xor(s1, 2); s2 += __shfl_xor(s2, 2);
        float m = s1 * (1.0f / 128.0f);
        float var = s2 * (1.0f / 128.0f) - m * m;
        float rstd = rsqrtf(var + EPSV);
        #pragma unroll
        for (int i = 0; i < 32; ++i)
            y3l[r][c0 + i] = f2bf((tv[i] - m) * rstd * g[c0 + i] + b[c0 + i]);
    }
    __syncthreads();

    f32x4 acc2[4][2];
    #pragma unroll
    for (int m = 0; m < 4; ++m)
        #pragma unroll
        for (int j = 0; j < 2; ++j) acc2[m][j] = (f32x4){0.f, 0.f, 0.f, 0.f};

    #pragma unroll
    for (int half = 0; half < 2; ++half) {
        // GEMM1 half: 256 DFF cols, wave covers 64 (4 j-tiles), M=64 (4 m-tiles)
        f32x4 acc[4][4];
        #pragma unroll
        for (int m = 0; m < 4; ++m)
            #pragma unroll
            for (int j = 0; j < 4; ++j) acc[m][j] = (f32x4){0.f, 0.f, 0.f, 0.f};
        int n0 = half * 256 + wv * 64;
        #pragma unroll
        for (int kk = 0; kk < 4; ++kk) {
            s16x8 a[4];
            #pragma unroll
            for (int m = 0; m < 4; ++m) a[m] = *(const s16x8*)&y3l[m * 16 + la][kk * 32 + kb];
            #pragma unroll
            for (int j = 0; j < 4; ++j) {
                s16x8 bf = *(const s16x8*)(w1t + (size_t)(n0 + j * 16 + la) * 128 + kk * 32 + kb);
                #pragma unroll
                for (int m = 0; m < 4; ++m)
                    acc[m][j] = __builtin_amdgcn_mfma_f32_16x16x32_bf16(a[m], bf, acc[m][j], 0, 0, 0);
            }
        }
        // bias + gelu -> hl (local col within half)
        #pragma unroll
        for (int j = 0; j < 4; ++j) {
            int lcol = wv * 64 + j * 16 + la;
            float bb = b1[half * 256 + lcol];
            #pragma unroll
            for (int m = 0; m < 4; ++m) {
                #pragma unroll
                for (int i = 0; i < 4; ++i) {
                    int row = m * 16 + hi * 4 + i;
                    hl[row][lcol] = f2bf(gelu_f(acc[m][j][i] + bb));
                }
            }
        }
        __syncthreads();
        // GEMM2 partial: K = this half's 256
        int n0b = wv * 32;
        #pragma unroll
        for (int kk = 0; kk < 8; ++kk) {
            s16x8 a[4];
            #pragma unroll
            for (int m = 0; m < 4; ++m) a[m] = *(const s16x8*)&hl[m * 16 + la][kk * 32 + kb];
            int gkk = half * 8 + kk;
            #pragma unroll
            for (int j = 0; j < 2; ++j) {
                s16x8 bf = *(const s16x8*)(w2t + (size_t)(n0b + j * 16 + la) * 512 + gkk * 32 + kb);
                #pragma unroll
                for (int m = 0; m < 4; ++m)
                    acc2[m][j] = __builtin_amdgcn_mfma_f32_16x16x32_bf16(a[m], bf, acc2[m][j], 0, 0, 0);
            }
        }
        __syncthreads();   // hl safe to overwrite next half
    }

    #pragma unroll
    for (int j = 0; j < 2; ++j) {
        int col = wv * 32 + j * 16 + la;
        float bb = b2[col];
        #pragma unroll
        for (int m = 0; m < 4; ++m) {
            #pragma unroll
            for (int i = 0; i < 4; ++i) {
                int row = m * 16 + hi * 4 + i;
                size_t grow = (size_t)(pos0 + row) * EE + col;
                x[grow] = y2[grow] + acc2[m][j][i] + bb;
            }
        }
    }
}

// ============ Decoder via MFMA ============
__global__ __launch_bounds__(256) void k_dec2(
    const float* __restrict__ x, const float* __restrict__ dct,
    const float* __restrict__ qt, const u16* __restrict__ dwb,
    const float* __restrict__ bd, float* __restrict__ out)
{
    int pos0 = blockIdx.x * 64;
    int n = pos0 >> 14;
    int hw0 = pos0 & 16383;
    int tid = threadIdx.x;
    int lane = tid & 63, wv = tid >> 6;
    int la = lane & 15, hi = lane >> 4, kb8 = hi * 8;
    __shared__ u16 al[64][136];

    for (int it = 0; it < 32; ++it) {
        int idx = it * 256 + tid;
        int r = idx >> 7, c = idx & 127;
        al[r][c] = f2bf(x[(size_t)(pos0 + r) * EE + c]);
    }
    __syncthreads();

    f32x4 acc[4];
    #pragma unroll
    for (int m = 0; m < 4; ++m) acc[m] = (f32x4){0.f, 0.f, 0.f, 0.f};
    #pragma unroll
    for (int kk = 0; kk < 4; ++kk) {
        s16x8 bf = *(const s16x8*)(dwb + (wv * 16 + la) * 128 + kk * 32 + kb8);
        #pragma unroll
        for (int m = 0; m < 4; ++m) {
            s16x8 a = *(const s16x8*)&al[m * 16 + la][kk * 32 + kb8];
            acc[m] = __builtin_amdgcn_mfma_f32_16x16x32_bf16(a, bf, acc[m], 0, 0, 0);
        }
    }
    int co = wv * 16 + la;
    float qv = qt[n * 64 + co];
    float bb = bd[co];
    #pragma unroll
    for (int m = 0; m < 4; ++m) {
        int p = m * 16 + hi * 4;
        size_t off = ((size_t)(n * 64 + co)) * HW + hw0 + p;
        float4 d4 = *reinterpret_cast<const float4*>(dct + off);
        float4 r;
        r.x = d4.x + (acc[m][0] + bb) * qv;
        r.y = d4.y + (acc[m][1] + bb) * qv;
        r.z = d4.z + (acc[m][2] + bb) * qv;
        r.w = d4.w + (acc[m][3] + bb) * qv;
        *reinterpret_cast<float4*>(out + off) = r;
    }
}

extern "C" void kernel_launch(void* const* d_in, const int* in_sizes, int n_in,
                              void* d_out, int out_size, void* d_ws, size_t ws_size,
                              hipStream_t stream) {
    const float* dct  = (const float*)d_in[0];
    const float* qt   = (const float*)d_in[1];
    const float* ec1w = (const float*)d_in[2];
    const float* ec1b = (const float*)d_in[3];
    const float* ec2w = (const float*)d_in[4];
    const float* ec2b = (const float*)d_in[5];
    const float* ln1g = (const float*)d_in[6];
    const float* ln1b = (const float*)d_in[7];
    const float* qw   = (const float*)d_in[8];
    const float* qb   = (const float*)d_in[9];
    const float* kw   = (const float*)d_in[10];
    const float* kb   = (const float*)d_in[11];
    const float* vw   = (const float*)d_in[12];
    const float* vb   = (const float*)d_in[13];
    const float* rb   = (const float*)d_in[14];
    const float* ln2g = (const float*)d_in[15];
    const float* ln2b = (const float*)d_in[16];
    const float* fw1  = (const float*)d_in[17];
    const float* fb1  = (const float*)d_in[18];
    const float* fw2  = (const float*)d_in[19];
    const float* fb2  = (const float*)d_in[20];
    const float* dw   = (const float*)d_in[21];
    const float* db   = (const float*)d_in[22];

    char* ws = (char*)d_ws;
    float* xbuf  = (float*)ws;                         // 67108864 B
    float* y2buf = (float*)(ws + 67108864);            // 67108864 B
    u16*   qbuf  = (u16*)(ws + 134217728);             // 33554432 B
    u16*   kbuf  = (u16*)(ws + 167772160);             // 33554432 B
    u16*   vbuf  = (u16*)(ws + 201326592);             // 33554432 B
    size_t woff = 234881024;
    u16* wqkvt = (u16*)(ws + woff);                    // 393216 B
    u16* w1t   = (u16*)(ws + woff + 393216);           // 524288 B
    u16* w2t   = (u16*)(ws + woff + 917504);           // 524288 B
    u16* wtap  = (u16*)(ws + woff + 1441792);          // 73728 B
    u16* w2b   = (u16*)(ws + woff + 1515520);          // 16384 B
    u16* dwb   = (u16*)(ws + woff + 1531904);          // 16384 B

    k_prep_qkvff<<<dim3(2816), dim3(256), 0, stream>>>(qw, kw, vw, fw1, fw2, wqkvt, w1t, w2t);
    k_prep_conv<<<dim3(208), dim3(256), 0, stream>>>(ec1w, ec2w, dw, wtap, w2b, dwb);

    k_enc_conv3<<<dim3(NB * HB), dim3(256), 0, stream>>>(dct, qt, wtap, ec1b, w2b, ec2b, xbuf);
    for (int l = 0; l < NLAY; ++l) {
        k_qkv3<<<dim3(NPOS / 64), dim3(256), 0, stream>>>(
            xbuf, ln1g + l * EE, ln1b + l * EE,
            wqkvt + l * 49152,
            qb + l * EE, kb + l * EE, vb + l * EE,
            qbuf, kbuf, vbuf);
        k_attn3<<<dim3(NB * 32 * 8 * 4), dim3(256), 0, stream>>>(
            qbuf, kbuf, vbuf, rb + l * NHD * PP, y2buf);
        k_ff4<<<dim3(NPOS / 64), dim3(256), 0, stream>>>(
            xbuf, y2buf, ln2g + l * EE, ln2b + l * EE,
            w1t + l * 65536, fb1 + l * DFF,
            w2t + l * 65536, fb2 + l * EE);
    }
    k_dec2<<<dim3(NPOS / 64), dim3(256), 0, stream>>>(
        xbuf, dct, qt, dwb, db, (float*)d_out);
}